// Round 4
// baseline (522.031 us; speedup 1.0000x reference)
//
#include <hip/hip_runtime.h>
#include <stdint.h>

// Problem constants
#define NODES   64
#define FDIM    256
#define ODIM    256
#define BGRAPH  4096
#define TROWS   (NODES * BGRAPH)   // 262144

// GEMM tile: full-K A panel in LDS; B direct L2->reg (no LDS, no K-loop barriers)
#define BM 64
#define BN 256
#define BK 32

typedef short  bf16x8  __attribute__((ext_vector_type(8)));
typedef float  floatx4 __attribute__((ext_vector_type(4)));

// RTNE fp32 -> bf16
__device__ inline unsigned short f2bf(float f) {
    unsigned int u = __float_as_uint(f);
    return (unsigned short)((u + 0x7fffu + ((u >> 16) & 1u)) >> 16);
}

// ---------------------------------------------------------------------------
// Kernel 1: W [node][f][o] fp32 -> Wt [node][o][f] bf16, 1/16 folded.
// (unchanged — verified)
// ---------------------------------------------------------------------------
__global__ __launch_bounds__(256) void transpose_w(const float* __restrict__ W,
                                                   unsigned short* __restrict__ Wt) {
    __shared__ unsigned short t[64][65];
    const int node = blockIdx.y;
    const int tf = (blockIdx.x >> 2) << 6;
    const int to = (blockIdx.x & 3) << 6;
    const int tid = threadIdx.x;
    const float* Wn = W + node * (FDIM * ODIM);
#pragma unroll
    for (int i = 0; i < 16; ++i) {
        int flat = i * 256 + tid;
        int r = flat >> 6, c = flat & 63;
        float v = Wn[(tf + r) * ODIM + (to + c)] * 0.0625f;
        t[c][r] = f2bf(v);
    }
    __syncthreads();
    unsigned short* Wtn = Wt + node * (FDIM * ODIM);
#pragma unroll
    for (int i = 0; i < 16; ++i) {
        int flat = i * 256 + tid;
        int r = flat >> 6, c = flat & 63;
        Wtn[(to + r) * FDIM + (tf + c)] = t[r][c];
    }
}

// ---------------------------------------------------------------------------
// Kernel 2: per-node GEMM, BM=64 x BN=256.
// 512 threads = 8 waves (2m x 4n); wave tile 32x64 = 2x4 mfma_16x16x32_bf16.
// A: full-K panel in LDS (32 KB), staged once as contiguous 1KB/row bursts,
//    XOR-swizzled (verified round 2/3). ONE barrier total.
// B: loaded directly L2 -> registers each K-step (Wt slice per XCD = 1 MB,
//    L2-resident; address is algebraically what the old Bs path delivered,
//    staging and read swizzles cancel). No Bs LDS, no K-loop barriers,
//    no vmcnt drains.
// Occupancy: 32 KB LDS, __launch_bounds__(512,4) -> 4 blocks/CU = 32 waves/CU
// (full). Grid 4096 = 4 exact residency rounds.
// ---------------------------------------------------------------------------
__global__ __launch_bounds__(512, 4) void gemm_node(const float* __restrict__ x,
                                                    const unsigned short* __restrict__ Wt,
                                                    float* __restrict__ out) {
    __shared__ __align__(16) unsigned short As[BM * 256];    // 32 KB, full K=256 panel

    // XCD-aware decode: blocks sharing a node land on the same XCD (L2 reuse)
    const int bid  = blockIdx.x;            // 0..4095
    const int xcd  = bid & 7;
    const int jj   = bid >> 3;              // 0..511
    const int node = xcd * 8 + (jj & 7);    // 8 nodes per XCD
    const int mblk = jj >> 3;               // 0..63
    const int b0   = mblk * BM;

    const int tid  = threadIdx.x;
    const int lane = tid & 63;
    const int wave = tid >> 6;              // 0..7
    const int wm   = wave >> 2;             // 0..1 -> 32 rows
    const int wn   = wave & 3;              // 0..3 -> 64 cols
    const int l15  = lane & 15;
    const int l4   = lane >> 4;

    const float* xblk = x + ((size_t)b0 * NODES + node) * FDIM;      // + row*16384 + f
    const unsigned short* wt_node = Wt + (size_t)node * (ODIM * FDIM);

    // Per-lane B base: row n = wn*64 + ni*16 + l15 of Wt[node], k-chunk l4*8.
    // b[ni](kt) = 16B at bbase + ni*16*FDIM + kt*32   (4 lanes/64B line, fully consumed)
    const unsigned short* bbase = wt_node + (size_t)(wn * 64 + l15) * FDIM + l4 * 8;

    // ---- issue B(kt=0) early: L2 latency overlaps the A-stage HBM bursts ----
    bf16x8 be[4], bo[4];
#pragma unroll
    for (int ni = 0; ni < 4; ++ni)
        be[ni] = *(const bf16x8*)(bbase + ni * 16 * FDIM);

    // ---- A panel: 64 rows x 1 KB contiguous each; q = i*512+tid: row=q>>6, ch=q&63
    //      each wave reads one full row per iteration -> perfect 1KB bursts.
    //      Store 8B chunk ch at 16B-slot (ch>>1)^(row&7), half (ch&1). ----
#pragma unroll
    for (int i = 0; i < 8; ++i) {
        const int q = i * 512 + tid;
        const int r = q >> 6, ch = q & 63;
        const float4 v = *(const float4*)(xblk + (size_t)r * (NODES * FDIM) + ch * 4);
        ushort4 p;
        p.x = f2bf(v.x); p.y = f2bf(v.y); p.z = f2bf(v.z); p.w = f2bf(v.w);
        const int slot = (ch >> 1) ^ (r & 7);
        *(ushort4*)(&As[r * 256 + slot * 8 + (ch & 1) * 4]) = p;
    }
    __syncthreads();   // the ONLY barrier

    floatx4 acc[2][4] = {};

#pragma unroll
    for (int kt = 0; kt < 8; ++kt) {
        // ---- prefetch B(kt+1) into the other register bank (no LDS, no barrier) ----
        if (kt < 7) {
            const int k1 = (kt + 1) * BK;
#pragma unroll
            for (int ni = 0; ni < 4; ++ni) {
                bf16x8 v = *(const bf16x8*)(bbase + ni * 16 * FDIM + k1);
                if (kt & 1) be[ni] = v; else bo[ni] = v;
            }
        }

        // ---- A fragments from LDS (swizzled; 2-way bank aliasing = free) ----
        bf16x8 a[2];
#pragma unroll
        for (int mi = 0; mi < 2; ++mi) {
            const int m = wm * 32 + mi * 16 + l15;
            const int slot = (kt * 4 + l4) ^ (m & 7);
            a[mi] = *(const bf16x8*)(&As[m * 256 + slot * 8]);
        }

        // ---- MFMA ----
#pragma unroll
        for (int mi = 0; mi < 2; ++mi)
#pragma unroll
            for (int ni = 0; ni < 4; ++ni) {
                const bf16x8 bf = (kt & 1) ? bo[ni] : be[ni];
                acc[mi][ni] = __builtin_amdgcn_mfma_f32_16x16x32_bf16(a[mi], bf, acc[mi][ni], 0, 0, 0);
            }
    }

    // ---- epilogue: C/D layout col = lane&15, row = (lane>>4)*4 + reg ----
    float* outblk = out + ((size_t)b0 * NODES + node) * ODIM;
#pragma unroll
    for (int mi = 0; mi < 2; ++mi) {
        const int row_base = wm * 32 + mi * 16 + l4 * 4;
#pragma unroll
        for (int ni = 0; ni < 4; ++ni) {
            const int col = wn * 64 + ni * 16 + l15;
#pragma unroll
            for (int r = 0; r < 4; ++r) {
                outblk[(size_t)(row_base + r) * (NODES * ODIM) + col] = acc[mi][ni][r];
            }
        }
    }
}

// ---------------------------------------------------------------------------
// Fallback (only if ws too small): fp32 naive.
// ---------------------------------------------------------------------------
__global__ __launch_bounds__(256) void naive_kernel(const float* __restrict__ x,
                                                    const float* __restrict__ W,
                                                    float* __restrict__ out) {
    __shared__ float xs[FDIM];
    const int row = blockIdx.x;
    const int node = row & (NODES - 1);
    const int o = threadIdx.x;
    xs[o] = x[(size_t)row * FDIM + o];
    __syncthreads();
    const float* Wn = W + (size_t)node * FDIM * ODIM;
    float s = 0.f;
#pragma unroll 8
    for (int f = 0; f < FDIM; ++f) s += xs[f] * Wn[(size_t)f * ODIM + o];
    out[(size_t)row * ODIM + o] = s * 0.0625f;
}

extern "C" void kernel_launch(void* const* d_in, const int* in_sizes, int n_in,
                              void* d_out, int out_size, void* d_ws, size_t ws_size,
                              hipStream_t stream) {
    const float* x = (const float*)d_in[0];
    // d_in[1] = batch (int64) — implied by row layout, unused
    const float* W = (const float*)d_in[2];
    float* out = (float*)d_out;

    const size_t wt_bytes = (size_t)NODES * ODIM * FDIM * sizeof(unsigned short); // 8.4 MB
    if (ws_size >= wt_bytes) {
        unsigned short* Wt = (unsigned short*)d_ws;
        transpose_w<<<dim3(16, NODES), 256, 0, stream>>>(W, Wt);
        gemm_node<<<dim3((BGRAPH / BM) * NODES), 512, 0, stream>>>(x, Wt, out);
    } else {
        naive_kernel<<<dim3(TROWS), 256, 0, stream>>>(x, W, out);
    }
}